// Round 4
// baseline (4011.431 us; speedup 1.0000x reference)
//
#include <hip/hip_runtime.h>
#include <hip/hip_fp16.h>
#include <cstdint>
#include <cstddef>

#define HIDDEN 4096
#define INTER  11008
#define NTOK   4096
#define NG1    (HIDDEN/64)   // 64
#define NG2    (INTER/64)    // 172
#define NSP    704512        // = 11008*64 = 4096*172 (elements per scale table)

typedef _Float16 f16;
typedef _Float16 f16x8 __attribute__((ext_vector_type(8)));
typedef float    f32x4 __attribute__((ext_vector_type(4)));

__device__ __forceinline__ void g2lds16(const void* g, void* l) {
  __builtin_amdgcn_global_load_lds(
      (const __attribute__((address_space(1))) uint32_t*)g,
      (__attribute__((address_space(3))) uint32_t*)l, 16, 0, 0);
}

// one packed word (byte: hi nibble = k even, lo = k odd) -> 2 f16: (q-z)*s
__device__ __forceinline__ uint32_t dq2(uint32_t b, __half2 s2, __half2 nzs) {
  uint32_t qb = 0x64006400u | (b >> 4) | ((b & 0xFu) << 16);
  __half2 hq = __builtin_bit_cast(__half2, qb);
  __half2 t  = __hsub2(hq, __builtin_bit_cast(__half2, 0x64006400u));
  return __builtin_bit_cast(uint32_t, __hfma2(t, s2, nzs));
}

// 4 packed words + fused scale-pair (lo16 = s, hi16 = -z*s) -> 8-wide f16 frag
__device__ __forceinline__ f16x8 dqfrag(uint4 w, uint32_t spair) {
  uint32_t slo = spair & 0xffffu;
  uint32_t shi = spair & 0xffff0000u;
  __half2 S = __builtin_bit_cast(__half2, slo | (slo << 16));
  __half2 Z = __builtin_bit_cast(__half2, shi | (shi >> 16));
  union { uint32_t u[4]; f16x8 v; } r;
  r.u[0] = dq2(w.x, S, Z); r.u[1] = dq2(w.y, S, Z);
  r.u[2] = dq2(w.z, S, Z); r.u[3] = dq2(w.w, S, Z);
  return r.v;
}

// ---------------- prepass: fuse (scale, zero) -> half2 (s, -z*s) in one u32
__global__ __launch_bounds__(256) void make_spairs(
    const float* __restrict__ s, const float* __restrict__ z,
    uint32_t* __restrict__ out, int n) {
  int i = blockIdx.x * 256 + threadIdx.x;
  if (i >= n) return;
  float sf = s[i], zf = z[i];
  uint32_t hs = __half_as_ushort(__float2half_rn(sf));
  uint32_t hn = __half_as_ushort(__float2half_rn(-zf * sf));
  out[i] = (hn << 16) | hs;
}

// ---------------- x: fp32 -> f16
__global__ __launch_bounds__(256) void cvt_x(const float* __restrict__ x,
                                             f16* __restrict__ xh) {
  size_t i = ((size_t)blockIdx.x * 256 + threadIdx.x) * 8;
  float4 a = *(const float4*)(x + i);
  float4 b = *(const float4*)(x + i + 4);
  f16x8 o = {(f16)a.x, (f16)a.y, (f16)a.z, (f16)a.w,
             (f16)b.x, (f16)b.y, (f16)b.z, (f16)b.w};
  *(f16x8*)(xh + i) = o;
}

// ---------------- GEMM1: h = silu(x Wg^T) * (x Wu^T)
// Block 256M x 64N dual, 8 waves (wm 0..3, wn 0..1), wave 64M x (32g+32u)N.
// A: LDS double-buffer via global_load_lds (x8 reuse). B: direct global->reg
// packed loads + in-register dequant (x4 wm dedup served by L1; no B LDS,
// ONE barrier per K-tile). LDS = 2 x 32 KB.
__global__ __launch_bounds__(512, 2) void gemm_gateup(
    const f16* __restrict__ xh,
    const uint32_t* __restrict__ gq, const uint32_t* __restrict__ uq,
    const uint32_t* __restrict__ gsp, const uint32_t* __restrict__ usp,
    f16* __restrict__ h) {
  __shared__ f16 lA[2][256 * 64];
  const int tid = threadIdx.x, lane = tid & 63, wave = tid >> 6;
  const int bn = blockIdx.x, bm = blockIdx.y;      // 172 x 16
  const int wm = wave >> 1, wn = wave & 1;
  const int col = lane & 15, q = lane >> 4;

  // A staging: 4 chunks/thread, rows i*64 + (tid>>3), global-side swizzle
  const int arow0 = tid >> 3;
  const int ak8s  = (tid & 7) ^ (arow0 & 7);
  const f16* aptr = xh + (size_t)(bm * 256 + arow0) * HIDDEN + ak8s * 8;
  const int aoff = tid * 16;

  // B: 4 (row, matrix) streams per lane: j 0,1 = gate in_ 0,1; j 2,3 = up
  const uint32_t* bptr[4];
  const uint32_t* spp[4];
#pragma unroll
  for (int in_ = 0; in_ < 2; ++in_) {
    int n = bn * 64 + wn * 32 + in_ * 16 + col;
    bptr[in_]     = gq + (size_t)n * (HIDDEN / 2) + q * 4;
    spp[in_]      = gsp + (size_t)n * NG1;
    bptr[2 + in_] = uq + (size_t)n * (HIDDEN / 2) + q * 4;
    spp[2 + in_]  = usp + (size_t)n * NG1;
  }

  // A fragment-read addressing
  int abase[4], asel[4];
#pragma unroll
  for (int im = 0; im < 4; ++im) {
    int r = wm * 64 + im * 16 + col;
    abase[im] = r * 128; asel[im] = r & 7;
  }

  f32x4 accg[4][2] = {};
  f32x4 accu[4][2] = {};

  auto stageA = [&](int kt, int buf) {
#pragma unroll
    for (int i = 0; i < 4; ++i)
      g2lds16(aptr + (size_t)kt * 64 + (size_t)i * 64 * HIDDEN,
              (char*)lA[buf] + aoff + i * 8192);
  };

  // prologue: tile 0
  uint4 pk[4][2]; uint32_t sw[4];
  stageA(0, 0);
#pragma unroll
  for (int j = 0; j < 4; ++j) {
    sw[j] = spp[j][0];
    pk[j][0] = *(const uint4*)(bptr[j]);
    pk[j][1] = *(const uint4*)(bptr[j] + 16);
  }

  for (int kt = 0; kt < NG1; ++kt) {
    __syncthreads();                       // A(kt) ready; drains prefetches
    if (kt + 1 < NG1) stageA(kt + 1, (kt + 1) & 1);
    const int nk = (kt + 1 < NG1) ? kt + 1 : kt;
    uint4 npk[4][2]; uint32_t nsw[4];
#pragma unroll
    for (int j = 0; j < 4; ++j) {
      nsw[j] = spp[j][nk];
      npk[j][0] = *(const uint4*)(bptr[j] + nk * 32);
      npk[j][1] = *(const uint4*)(bptr[j] + nk * 32 + 16);
    }
    // dequant current B to fragments
    f16x8 bf[4][2];
#pragma unroll
    for (int j = 0; j < 4; ++j) {
      bf[j][0] = dqfrag(pk[j][0], sw[j]);
      bf[j][1] = dqfrag(pk[j][1], sw[j]);
    }
    // compute
    const f16* A = lA[kt & 1];
#pragma unroll
    for (int ks = 0; ks < 2; ++ks) {
      int kc = ks * 4 + q;
      f16x8 a[4];
#pragma unroll
      for (int im = 0; im < 4; ++im)
        a[im] = *(const f16x8*)((const char*)A + abase[im] + ((kc ^ asel[im]) << 4));
#pragma unroll
      for (int im = 0; im < 4; ++im) {
#pragma unroll
        for (int in_ = 0; in_ < 2; ++in_) {
          accg[im][in_] = __builtin_amdgcn_mfma_f32_16x16x32_f16(a[im], bf[in_][ks], accg[im][in_], 0, 0, 0);
          accu[im][in_] = __builtin_amdgcn_mfma_f32_16x16x32_f16(a[im], bf[2 + in_][ks], accu[im][in_], 0, 0, 0);
        }
      }
    }
#pragma unroll
    for (int j = 0; j < 4; ++j) {
      sw[j] = nsw[j]; pk[j][0] = npk[j][0]; pk[j][1] = npk[j][1];
    }
  }

  // epilogue: h = silu(g)*u.  C/D: col=lane&15, row=(lane>>4)*4+r
#pragma unroll
  for (int im = 0; im < 4; ++im)
#pragma unroll
    for (int in_ = 0; in_ < 2; ++in_)
#pragma unroll
      for (int r = 0; r < 4; ++r) {
        int row = bm * 256 + wm * 64 + im * 16 + q * 4 + r;
        int c   = bn * 64 + wn * 32 + in_ * 16 + col;
        float g = accg[im][in_][r];
        float u = accu[im][in_][r];
        float hv = (g / (1.0f + __expf(-g))) * u;
        h[(size_t)row * INTER + c] = (f16)hv;
      }
}

// ---------------- GEMM2: out = h Wd^T (fp32 out)
// Block 256M x 128N, 8 waves (wm 0..3, wn 0..1), wave 64x64. Same structure.
__global__ __launch_bounds__(512, 2) void gemm_down(
    const f16* __restrict__ h, const uint32_t* __restrict__ dq_,
    const uint32_t* __restrict__ dsp, float* __restrict__ out) {
  __shared__ f16 lA[2][256 * 64];
  const int tid = threadIdx.x, lane = tid & 63, wave = tid >> 6;
  const int bn = blockIdx.x, bm = blockIdx.y;   // 32 x 16
  const int wm = wave >> 1, wn = wave & 1;
  const int col = lane & 15, q = lane >> 4;

  const int arow0 = tid >> 3;
  const int ak8s  = (tid & 7) ^ (arow0 & 7);
  const f16* aptr = h + (size_t)(bm * 256 + arow0) * INTER + ak8s * 8;
  const int aoff = tid * 16;

  const uint32_t* bptr[4];
  const uint32_t* spp[4];
#pragma unroll
  for (int j = 0; j < 4; ++j) {
    int n = bn * 128 + wn * 64 + j * 16 + col;
    bptr[j] = dq_ + (size_t)n * (INTER / 2) + q * 4;
    spp[j]  = dsp + (size_t)n * NG2;
  }

  int abase[4], asel[4];
#pragma unroll
  for (int im = 0; im < 4; ++im) {
    int r = wm * 64 + im * 16 + col;
    abase[im] = r * 128; asel[im] = r & 7;
  }

  f32x4 acc[4][4] = {};

  auto stageA = [&](int kt, int buf) {
#pragma unroll
    for (int i = 0; i < 4; ++i)
      g2lds16(aptr + (size_t)kt * 64 + (size_t)i * 64 * INTER,
              (char*)lA[buf] + aoff + i * 8192);
  };

  uint4 pk[4][2]; uint32_t sw[4];
  stageA(0, 0);
#pragma unroll
  for (int j = 0; j < 4; ++j) {
    sw[j] = spp[j][0];
    pk[j][0] = *(const uint4*)(bptr[j]);
    pk[j][1] = *(const uint4*)(bptr[j] + 16);
  }

  for (int kt = 0; kt < NG2; ++kt) {
    __syncthreads();
    if (kt + 1 < NG2) stageA(kt + 1, (kt + 1) & 1);
    const int nk = (kt + 1 < NG2) ? kt + 1 : kt;
    uint4 npk[4][2]; uint32_t nsw[4];
#pragma unroll
    for (int j = 0; j < 4; ++j) {
      nsw[j] = spp[j][nk];
      npk[j][0] = *(const uint4*)(bptr[j] + nk * 32);
      npk[j][1] = *(const uint4*)(bptr[j] + nk * 32 + 16);
    }
    f16x8 bf[4][2];
#pragma unroll
    for (int j = 0; j < 4; ++j) {
      bf[j][0] = dqfrag(pk[j][0], sw[j]);
      bf[j][1] = dqfrag(pk[j][1], sw[j]);
    }
    const f16* A = lA[kt & 1];
#pragma unroll
    for (int ks = 0; ks < 2; ++ks) {
      int kc = ks * 4 + q;
      f16x8 a[4];
#pragma unroll
      for (int im = 0; im < 4; ++im)
        a[im] = *(const f16x8*)((const char*)A + abase[im] + ((kc ^ asel[im]) << 4));
#pragma unroll
      for (int im = 0; im < 4; ++im)
#pragma unroll
        for (int j = 0; j < 4; ++j)
          acc[im][j] = __builtin_amdgcn_mfma_f32_16x16x32_f16(a[im], bf[j][ks], acc[im][j], 0, 0, 0);
    }
#pragma unroll
    for (int j = 0; j < 4; ++j) {
      sw[j] = nsw[j]; pk[j][0] = npk[j][0]; pk[j][1] = npk[j][1];
    }
  }

#pragma unroll
  for (int im = 0; im < 4; ++im)
#pragma unroll
    for (int j = 0; j < 4; ++j)
#pragma unroll
      for (int r = 0; r < 4; ++r) {
        int row = bm * 256 + wm * 64 + im * 16 + q * 4 + r;
        int c   = bn * 128 + wn * 64 + j * 16 + col;
        out[(size_t)row * HIDDEN + c] = acc[im][j][r];
      }
}

// ---------------- launcher
extern "C" void kernel_launch(void* const* d_in, const int* in_sizes, int n_in,
                              void* d_out, int out_size, void* d_ws, size_t ws_size,
                              hipStream_t stream) {
  const float*    x   = (const float*)d_in[0];
  const uint32_t* gq  = (const uint32_t*)d_in[1];
  const uint32_t* uq  = (const uint32_t*)d_in[2];
  const uint32_t* dqw = (const uint32_t*)d_in[3];
  const float*    gs  = (const float*)d_in[4];
  const float*    gz  = (const float*)d_in[5];
  const float*    us  = (const float*)d_in[6];
  const float*    uz  = (const float*)d_in[7];
  const float*    dsc = (const float*)d_in[8];
  const float*    dzz = (const float*)d_in[9];

  char* ws = (char*)d_ws;
  const size_t SPB = (size_t)NSP * 4;           // 2.82 MB per table
  uint32_t* gsp = (uint32_t*)(ws);
  uint32_t* usp = (uint32_t*)(ws + SPB);
  uint32_t* dsp = (uint32_t*)(ws + 2 * SPB);
  f16* xh   = (f16*)(ws + 3 * SPB);
  f16* hbuf = (f16*)(ws + 3 * SPB + (size_t)NTOK * HIDDEN * 2);
  float* out = (float*)d_out;

  const int spg = (NSP + 255) / 256;
  make_spairs<<<spg, 256, 0, stream>>>(gs, gz, gsp, NSP);
  make_spairs<<<spg, 256, 0, stream>>>(us, uz, usp, NSP);
  make_spairs<<<spg, 256, 0, stream>>>(dsc, dzz, dsp, NSP);
  cvt_x<<<dim3((NTOK * HIDDEN) / (256 * 8)), 256, 0, stream>>>(x, xh);
  gemm_gateup<<<dim3(INTER / 64, NTOK / 256), 512, 0, stream>>>(
      xh, gq, uq, gsp, usp, hbuf);
  gemm_down<<<dim3(HIDDEN / 128, NTOK / 256), 512, 0, stream>>>(
      hbuf, dqw, dsp, out);
}

// Round 5
// 1691.792 us; speedup vs baseline: 2.3711x; 2.3711x over previous
//
#include <hip/hip_runtime.h>
#include <hip/hip_fp16.h>
#include <cstdint>
#include <cstddef>

#define HIDDEN 4096
#define INTER  11008
#define NTOK   4096
#define NG1    (HIDDEN/64)   // 64
#define NG2    (INTER/64)    // 172
#define NSP    704512        // 11008*64 == 4096*172

typedef _Float16 f16;
typedef _Float16 f16x8 __attribute__((ext_vector_type(8)));
typedef float    f32x4 __attribute__((ext_vector_type(4)));

__device__ __forceinline__ void g2lds16(const void* g, void* l) {
  __builtin_amdgcn_global_load_lds(
      (const __attribute__((address_space(1))) uint32_t*)g,
      (__attribute__((address_space(3))) uint32_t*)l, 16, 0, 0);
}

// one packed word (byte: hi nibble = k even, lo = k odd) -> 2 f16: (q-z)*s
__device__ __forceinline__ uint32_t dq2(uint32_t b, __half2 s2, __half2 nzs) {
  uint32_t qb = 0x64006400u | (b >> 4) | ((b & 0xFu) << 16);
  __half2 hq = __builtin_bit_cast(__half2, qb);
  __half2 t  = __hsub2(hq, __builtin_bit_cast(__half2, 0x64006400u));
  return __builtin_bit_cast(uint32_t, __hfma2(t, s2, nzs));
}

// spair: lo16 = s (f16), hi16 = -z*s (f16)
__device__ __forceinline__ uint4 dqchunk(uint4 w, uint32_t spair) {
  uint32_t slo = spair & 0xffffu;
  uint32_t shi = spair & 0xffff0000u;
  __half2 S = __builtin_bit_cast(__half2, slo | (slo << 16));
  __half2 Z = __builtin_bit_cast(__half2, shi | (shi >> 16));
  uint4 o;
  o.x = dq2(w.x, S, Z); o.y = dq2(w.y, S, Z);
  o.z = dq2(w.z, S, Z); o.w = dq2(w.w, S, Z);
  return o;
}

// ---------------- prepass: fuse (scale, zero) -> (s, -z*s) f16 pair
__global__ __launch_bounds__(256) void make_spairs(
    const float* __restrict__ s, const float* __restrict__ z,
    uint32_t* __restrict__ out, int n) {
  int i = blockIdx.x * 256 + threadIdx.x;
  if (i >= n) return;
  float sf = s[i], zf = z[i];
  uint32_t hs = __half_as_ushort(__float2half_rn(sf));
  uint32_t hn = __half_as_ushort(__float2half_rn(-zf * sf));
  out[i] = (hn << 16) | hs;
}

// ---------------- x: fp32 -> f16
__global__ __launch_bounds__(256) void cvt_x(const float* __restrict__ x,
                                             f16* __restrict__ xh) {
  size_t i = ((size_t)blockIdx.x * 256 + threadIdx.x) * 8;
  float4 a = *(const float4*)(x + i);
  float4 b = *(const float4*)(x + i + 4);
  f16x8 o = {(f16)a.x, (f16)a.y, (f16)a.z, (f16)a.w,
             (f16)b.x, (f16)b.y, (f16)b.z, (f16)b.w};
  *(f16x8*)(xh + i) = o;
}

// ============ GEMM1: h = silu(x Wg^T) * (x Wu^T) ============
// Block 256M x 128N dual. 512 thr = 8 waves (wm 0..3, wn 0..1).
// Wave tile 64M x 64N PER MATRIX -> acc 128 VGPR. BK=64 = 1 quant group.
// A dbuf 2x32K + B dbuf 2x(16K gate + 16K up) = 128 KB dynamic -> 1 block/CU.
// ONE barrier per K-tile; packed B register-prefetched one tile ahead
// (coalesced row-major loads); A via async DMA one tile ahead.
__global__ __launch_bounds__(512, 2) void gemm_gateup(
    const f16* __restrict__ xh,
    const uint32_t* __restrict__ gq, const uint32_t* __restrict__ uq,
    const uint32_t* __restrict__ gsp, const uint32_t* __restrict__ usp,
    f16* __restrict__ h) {
  extern __shared__ char smem[];
  // layout: A buf0 @0 (32K), A buf1 @32K, B buf0 @64K (gate 16K + up 16K),
  //         B buf1 @96K
  const int tid = threadIdx.x, lane = tid & 63, wave = tid >> 6;
  const int bm = blockIdx.x, bn = blockIdx.y;     // 16 x 86
  const int wm = wave >> 1, wn = wave & 1;
  const int col = lane & 15, q = lane >> 4;

  // ---- A staging: 4 chunks/thread (rows tid>>3 + i*64), global-side swizzle
  const int arow0 = tid >> 3;
  const int ak8s  = (tid & 7) ^ (arow0 & 7);
  const f16* aptr = xh + (size_t)(bm * 256 + arow0) * HIDDEN + ak8s * 8;
  const int aoff = tid * 16;

  // ---- B staging: per thread 4 chunks = gate rows r0,r0+64 + up rows r0,r0+64
  const int r0 = tid >> 3, k8 = tid & 7;
  const uint32_t* gp0 = gq + (size_t)(bn * 128 + r0) * (HIDDEN / 2) + k8 * 4;
  const uint32_t* up0 = uq + (size_t)(bn * 128 + r0) * (HIDDEN / 2) + k8 * 4;
  const uint32_t* gsp0 = gsp + (size_t)(bn * 128 + r0) * NG1;
  const uint32_t* usp0 = usp + (size_t)(bn * 128 + r0) * NG1;
  const int ROWSTEP = 64 * (HIDDEN / 2);          // +64 weight rows
  const int bws = r0 * 128 + (((k8) ^ (r0 & 7)) << 4);  // (r0+64)&7 == r0&7

  // ---- fragment-read addressing (hoisted)
  int abase[4], asel[4];
#pragma unroll
  for (int im = 0; im < 4; ++im) {
    int r = wm * 64 + im * 16 + col;
    abase[im] = r * 128; asel[im] = r & 7;
  }
  int bbase[4], bsel[4];
#pragma unroll
  for (int jn = 0; jn < 4; ++jn) {
    int r = wn * 64 + jn * 16 + col;
    bbase[jn] = r * 128; bsel[jn] = r & 7;
  }

  f32x4 accg[4][4] = {};
  f32x4 accu[4][4] = {};

  auto stageA = [&](int kt, int buf) {
#pragma unroll
    for (int i = 0; i < 4; ++i)
      g2lds16(aptr + (size_t)kt * 64 + (size_t)i * 64 * HIDDEN,
              smem + buf * 32768 + aoff + i * 8192);
  };
  auto loadPk = [&](int kt, uint4* w, uint32_t* sp) {
    w[0] = *(const uint4*)(gp0 + kt * 32);
    w[1] = *(const uint4*)(gp0 + ROWSTEP + kt * 32);
    w[2] = *(const uint4*)(up0 + kt * 32);
    w[3] = *(const uint4*)(up0 + ROWSTEP + kt * 32);
    sp[0] = gsp0[kt]; sp[1] = gsp0[64 * NG1 + kt];
    sp[2] = usp0[kt]; sp[3] = usp0[64 * NG1 + kt];
  };
  auto writeB = [&](const uint4* w, const uint32_t* sp, int buf) {
    char* base = smem + 65536 + buf * 32768;
    *(uint4*)(base + bws)              = dqchunk(w[0], sp[0]);  // gate r0
    *(uint4*)(base + bws + 64 * 128)   = dqchunk(w[1], sp[1]);  // gate r0+64
    *(uint4*)(base + 16384 + bws)            = dqchunk(w[2], sp[2]); // up r0
    *(uint4*)(base + 16384 + bws + 64 * 128) = dqchunk(w[3], sp[3]); // up r0+64
  };
  auto compute = [&](int buf) {
    const char* A = smem + buf * 32768;
    const char* B = smem + 65536 + buf * 32768;
#pragma unroll
    for (int ks = 0; ks < 2; ++ks) {
      int kc = ks * 4 + q;
      f16x8 a[4];
#pragma unroll
      for (int im = 0; im < 4; ++im)
        a[im] = *(const f16x8*)(A + abase[im] + ((kc ^ asel[im]) << 4));
#pragma unroll
      for (int jn = 0; jn < 4; ++jn) {
        f16x8 bg = *(const f16x8*)(B + bbase[jn] + ((kc ^ bsel[jn]) << 4));
        f16x8 bu = *(const f16x8*)(B + 16384 + bbase[jn] + ((kc ^ bsel[jn]) << 4));
#pragma unroll
        for (int im = 0; im < 4; ++im) {
          accg[im][jn] = __builtin_amdgcn_mfma_f32_16x16x32_f16(a[im], bg, accg[im][jn], 0, 0, 0);
          accu[im][jn] = __builtin_amdgcn_mfma_f32_16x16x32_f16(a[im], bu, accu[im][jn], 0, 0, 0);
        }
      }
    }
  };

  // ---- prologue: tile 0 staged; packed tile 1 in regs
  uint4 w[4]; uint32_t sp[4];
  stageA(0, 0);
  loadPk(0, w, sp);
  writeB(w, sp, 0);
  loadPk(1 < NG1 ? 1 : 0, w, sp);
  __syncthreads();

  for (int kt = 0; kt < NG1; ++kt) {
    const int p = kt & 1;
    const int nk = (kt + 1 < NG1) ? kt + 1 : kt;     // clamp (safe redundant)
    stageA(nk, p ^ 1);                                // A(kt+1) DMA -> alt buf
    writeB(w, sp, p ^ 1);                             // B(kt+1) -> alt buf
    uint4 nw[4]; uint32_t nsp[4];
    const int nk2 = (kt + 2 < NG1) ? kt + 2 : nk;
    loadPk(nk2, nw, nsp);                             // packed B(kt+2) -> regs
    compute(p);                                       // tile kt
#pragma unroll
    for (int j = 0; j < 4; ++j) { w[j] = nw[j]; sp[j] = nsp[j]; }
    __syncthreads();                                  // single barrier
  }

  // ---- epilogue: h = silu(g)*u.  C/D: col=lane&15, row=(lane>>4)*4+r
#pragma unroll
  for (int im = 0; im < 4; ++im)
#pragma unroll
    for (int jn = 0; jn < 4; ++jn)
#pragma unroll
      for (int r = 0; r < 4; ++r) {
        int row = bm * 256 + wm * 64 + im * 16 + q * 4 + r;
        int c   = bn * 128 + wn * 64 + jn * 16 + col;
        float g = accg[im][jn][r];
        float u = accu[im][jn][r];
        float hv = (g / (1.0f + __expf(-g))) * u;
        h[(size_t)row * INTER + c] = (f16)hv;
      }
}

// ============ GEMM2: out = h Wd^T (fp32) ============
// Block 256M x 256N. 512 thr = 8 waves (wm 0..3, wn 0..1).
// Wave tile 64M x 128N -> acc 128 VGPR. Grid 16x16 = 256 blocks = 1/CU.
// A dbuf 2x32K + B dbuf 2x32K = 128 KB. Single barrier per K-tile.
__global__ __launch_bounds__(512, 2) void gemm_down(
    const f16* __restrict__ h, const uint32_t* __restrict__ dq_,
    const uint32_t* __restrict__ dsp, float* __restrict__ out) {
  extern __shared__ char smem[];
  const int tid = threadIdx.x, lane = tid & 63, wave = tid >> 6;
  const int bm = blockIdx.x, bn = blockIdx.y;     // 16 x 16
  const int wm = wave >> 1, wn = wave & 1;
  const int col = lane & 15, q = lane >> 4;

  const int arow0 = tid >> 3;
  const int ak8s  = (tid & 7) ^ (arow0 & 7);
  const f16* aptr = h + (size_t)(bm * 256 + arow0) * INTER + ak8s * 8;
  const int aoff = tid * 16;

  // B staging: 4 chunks/thread = rows r0 + {0,64,128,192}
  const int r0 = tid >> 3, k8 = tid & 7;
  const uint32_t* dp0 = dq_ + (size_t)(bn * 256 + r0) * (INTER / 2) + k8 * 4;
  const uint32_t* dsp0 = dsp + (size_t)(bn * 256 + r0) * NG2;
  const int ROWSTEP = 64 * (INTER / 2);
  const int bws = r0 * 128 + ((k8 ^ (r0 & 7)) << 4);

  int abase[4], asel[4];
#pragma unroll
  for (int im = 0; im < 4; ++im) {
    int r = wm * 64 + im * 16 + col;
    abase[im] = r * 128; asel[im] = r & 7;
  }
  int bbase[8], bsel[8];
#pragma unroll
  for (int jn = 0; jn < 8; ++jn) {
    int r = wn * 128 + jn * 16 + col;
    bbase[jn] = r * 128; bsel[jn] = r & 7;
  }

  f32x4 acc[4][8] = {};

  auto stageA = [&](int kt, int buf) {
#pragma unroll
    for (int i = 0; i < 4; ++i)
      g2lds16(aptr + (size_t)kt * 64 + (size_t)i * 64 * INTER,
              smem + buf * 32768 + aoff + i * 8192);
  };
  auto loadPk = [&](int kt, uint4* w, uint32_t* sp) {
#pragma unroll
    for (int j = 0; j < 4; ++j) {
      w[j] = *(const uint4*)(dp0 + j * ROWSTEP + kt * 32);
      sp[j] = dsp0[j * 64 * NG2 + kt];
    }
  };
  auto writeB = [&](const uint4* w, const uint32_t* sp, int buf) {
    char* base = smem + 65536 + buf * 32768;
#pragma unroll
    for (int j = 0; j < 4; ++j)
      *(uint4*)(base + bws + j * 64 * 128) = dqchunk(w[j], sp[j]);
  };
  auto compute = [&](int buf) {
    const char* A = smem + buf * 32768;
    const char* B = smem + 65536 + buf * 32768;
#pragma unroll
    for (int ks = 0; ks < 2; ++ks) {
      int kc = ks * 4 + q;
      f16x8 a[4];
#pragma unroll
      for (int im = 0; im < 4; ++im)
        a[im] = *(const f16x8*)(A + abase[im] + ((kc ^ asel[im]) << 4));
#pragma unroll
      for (int jn = 0; jn < 8; ++jn) {
        f16x8 b = *(const f16x8*)(B + bbase[jn] + ((kc ^ bsel[jn]) << 4));
#pragma unroll
        for (int im = 0; im < 4; ++im)
          acc[im][jn] = __builtin_amdgcn_mfma_f32_16x16x32_f16(a[im], b, acc[im][jn], 0, 0, 0);
      }
    }
  };

  uint4 w[4]; uint32_t sp[4];
  stageA(0, 0);
  loadPk(0, w, sp);
  writeB(w, sp, 0);
  loadPk(1, w, sp);
  __syncthreads();

  for (int kt = 0; kt < NG2; ++kt) {
    const int p = kt & 1;
    const int nk = (kt + 1 < NG2) ? kt + 1 : kt;
    stageA(nk, p ^ 1);
    writeB(w, sp, p ^ 1);
    uint4 nw[4]; uint32_t nsp[4];
    const int nk2 = (kt + 2 < NG2) ? kt + 2 : nk;
    loadPk(nk2, nw, nsp);
    compute(p);
#pragma unroll
    for (int j = 0; j < 4; ++j) { w[j] = nw[j]; sp[j] = nsp[j]; }
    __syncthreads();
  }

#pragma unroll
  for (int im = 0; im < 4; ++im)
#pragma unroll
    for (int jn = 0; jn < 8; ++jn)
#pragma unroll
      for (int r = 0; r < 4; ++r) {
        int row = bm * 256 + wm * 64 + im * 16 + q * 4 + r;
        int c   = bn * 256 + wn * 128 + jn * 16 + col;
        out[(size_t)row * HIDDEN + c] = acc[im][jn][r];
      }
}

// ---------------- launcher
extern "C" void kernel_launch(void* const* d_in, const int* in_sizes, int n_in,
                              void* d_out, int out_size, void* d_ws, size_t ws_size,
                              hipStream_t stream) {
  const float*    x   = (const float*)d_in[0];
  const uint32_t* gq  = (const uint32_t*)d_in[1];
  const uint32_t* uq  = (const uint32_t*)d_in[2];
  const uint32_t* dqw = (const uint32_t*)d_in[3];
  const float*    gs  = (const float*)d_in[4];
  const float*    gz  = (const float*)d_in[5];
  const float*    us  = (const float*)d_in[6];
  const float*    uz  = (const float*)d_in[7];
  const float*    dsc = (const float*)d_in[8];
  const float*    dzz = (const float*)d_in[9];

  char* ws = (char*)d_ws;
  const size_t SPB = (size_t)NSP * 4;
  uint32_t* gsp = (uint32_t*)(ws);
  uint32_t* usp = (uint32_t*)(ws + SPB);
  uint32_t* dsp = (uint32_t*)(ws + 2 * SPB);
  f16* xh   = (f16*)(ws + 3 * SPB);
  f16* hbuf = (f16*)(ws + 3 * SPB + (size_t)NTOK * HIDDEN * 2);
  float* out = (float*)d_out;

  const int LDS_BYTES = 128 * 1024;
  (void)hipFuncSetAttribute((const void*)gemm_gateup,
                            hipFuncAttributeMaxDynamicSharedMemorySize, LDS_BYTES);
  (void)hipFuncSetAttribute((const void*)gemm_down,
                            hipFuncAttributeMaxDynamicSharedMemorySize, LDS_BYTES);

  const int spg = (NSP + 255) / 256;
  make_spairs<<<spg, 256, 0, stream>>>(gs, gz, gsp, NSP);
  make_spairs<<<spg, 256, 0, stream>>>(us, uz, usp, NSP);
  make_spairs<<<spg, 256, 0, stream>>>(dsc, dzz, dsp, NSP);
  cvt_x<<<dim3((NTOK * HIDDEN) / (256 * 8)), 256, 0, stream>>>(x, xh);
  gemm_gateup<<<dim3(NTOK / 256, INTER / 128), 512, LDS_BYTES, stream>>>(
      xh, gq, uq, gsp, usp, hbuf);
  gemm_down<<<dim3(NTOK / 256, HIDDEN / 256), 512, LDS_BYTES, stream>>>(
      hbuf, dqw, dsp, out);
}